// Round 1
// baseline (93.098 us; speedup 1.0000x reference)
//
#include <hip/hip_runtime.h>
#include <math.h>

#define MB_    32
#define ATOM_  64
#define HID_   64
#define NRBF_  300
#define GAMMA_ 10.0f
#define RES_   0.1f

// filter table: f2(d) sampled at TPTS points, step TSTEP, domain [0, 10]
#define TPTS      2001
#define TSTEP     0.005f
#define INV_TSTEP 200.0f

// truncated RBF window: terms with |d - 0.1 r| > ~1.4 contribute < 5e-9
#define RWIN 28
// staged Wd1 window rows per block (covers per-wave r0 offset 0..1 + RWIN)
#define NSTG 32

// workspace layout (float offsets)
// table stored as interleaved pairs: T2[s][c] = (f[s][c], f[s+1][c])
#define T2_OFF  0
#define T2_SZ   (TPTS * 128)          // 256128
#define V1_OFF  (T2_OFF + T2_SZ)      // 256128
#define V1_SZ   (MB_ * 64 * 64)       // 131072
#define W2T_OFF (V1_OFF + V1_SZ)      // 387200
#define W3T_OFF (W2T_OFF + 4096)      // 391296
// total 395392 floats = 1,581,568 bytes of d_ws

__device__ __forceinline__ float sp_f(float x) {
    return fmaxf(x, 0.f) + log1pf(__expf(-fabsf(x)));
}

// ---------------------------------------------------------------------------
// prep: blocks [0,32)   -> v1[m] = x[m] @ W1^T + b1   (4x4 register tile)
//       blocks [32,533) -> filter table rows; Wd1 window + Wd2^T staged in
//                          LDS (coalesced) so inner loops are conflict-free
//                          ds_reads instead of 64-way-split global gathers
//       block  533      -> W2^T, W3^T for coalesced tail reads
// ---------------------------------------------------------------------------
__global__ __launch_bounds__(256)
void schnet_prep(const float* __restrict__ x,   const float* __restrict__ W1,
                 const float* __restrict__ b1,  const float* __restrict__ W2,
                 const float* __restrict__ W3,  const float* __restrict__ Wd1,
                 const float* __restrict__ bd1, const float* __restrict__ Wd2,
                 const float* __restrict__ bd2, float* __restrict__ ws)
{
    __shared__ float smem[8320];     // 33.3 KB, unioned between branches
    const int tid = threadIdx.x;
    const int b   = blockIdx.x;

    if (b < MB_) {
        // ---- v1 = x[m] @ W1^T + b1, 4x4 register tile per thread ----
        float* sx = smem;            // x[m]  [64][65] (pad -> <=2-way banks)
        float* sw = smem + 4160;     // W1    [64][65]
        const float* xm = x + b * 4096;
        for (int e = tid; e < 4096; e += 256) {
            int i = e >> 6, cc = e & 63;
            sx[i * 65 + cc] = xm[e];
            sw[i * 65 + cc] = W1[e];
        }
        __syncthreads();
        const int tx = tid & 15;         // o-tile: o = 4*tx + bb
        const int ty = tid >> 4;         // i-tile: i = 4*ty + aa
        float acc[4][4];
        #pragma unroll
        for (int aa = 0; aa < 4; ++aa)
            #pragma unroll
            for (int bb = 0; bb < 4; ++bb)
                acc[aa][bb] = b1[4 * tx + bb];
        #pragma unroll 8
        for (int k = 0; k < 64; ++k) {
            float xa[4], wb[4];
            #pragma unroll
            for (int aa = 0; aa < 4; ++aa) xa[aa] = sx[(4 * ty + aa) * 65 + k];  // broadcast
            #pragma unroll
            for (int bb = 0; bb < 4; ++bb) wb[bb] = sw[(4 * tx + bb) * 65 + k];  // 2-way
            #pragma unroll
            for (int aa = 0; aa < 4; ++aa)
                #pragma unroll
                for (int bb = 0; bb < 4; ++bb)
                    acc[aa][bb] = fmaf(xa[aa], wb[bb], acc[aa][bb]);
        }
        #pragma unroll
        for (int aa = 0; aa < 4; ++aa) {
            float4 v = make_float4(acc[aa][0], acc[aa][1], acc[aa][2], acc[aa][3]);
            *(float4*)(ws + V1_OFF + (b * 64 + 4 * ty + aa) * 64 + 4 * tx) = v;
        }
    } else if (b < MB_ + 501) {
        // ---- table: one d-sample per wave, truncated RBF, LDS-staged weights
        float* sWd1  = smem;                 // [NSTG][65]  : 2080 floats
        float* sWd2T = smem + NSTG * 65;     // [64][65]    : 4160 floats
        float* su    = smem + NSTG * 65 + 4160;  // [4][64] : 256 floats

        const int sub = tid >> 6, c = tid & 63;
        const int s  = (b - MB_) * 4 + sub;
        const int se = min(s, TPTS - 1);         // dead waves compute, don't store
        const float d = se * TSTEP;

        // block-wide Wd1 window base (from the block's smallest d)
        const int s0 = (b - MB_) * 4;
        int rb0 = (int)ceilf((s0 * TSTEP - 1.35f) * 10.0f);
        rb0 = max(rb0, 0);
        // per-wave window start (rb0 <= r0 <= rb0+1 by construction)
        int r0 = (int)ceilf((d - 1.35f) * 10.0f);
        r0 = max(r0, 0);                          // r0+RWIN-1 <= 114 < 300 always

        // stage Wd1[*, rb0:rb0+NSTG) transposed -> sWd1[k][c]; coalesced reads,
        // conflict-free stores (bank = (k+c)&31)
        #pragma unroll
        for (int it = 0; it < (NSTG * 64) / 256; ++it) {
            int idx = tid + it * 256;
            int k   = idx & (NSTG - 1);
            int cc  = idx >> 5;                   // NSTG==32
            sWd1[k * 65 + cc] = Wd1[cc * NRBF_ + rb0 + k];
        }
        // stage Wd2 transposed -> sWd2T[h][o]; coalesced reads, conflict-free
        #pragma unroll
        for (int it = 0; it < 4096 / 256; ++it) {
            int idx = tid + it * 256;
            int h = idx & 63, o = idx >> 6;
            sWd2T[h * 65 + o] = Wd2[idx];
        }
        __syncthreads();

        float a0 = bd1[c], a1 = 0.f;
        const float* wr = sWd1 + (r0 - rb0) * 65 + c;   // lane reads: <=2-way banks
        #pragma unroll
        for (int k = 0; k < RWIN; k += 2) {
            float t0 = fmaf(-RES_, (float)(r0 + k),     d);
            float t1 = fmaf(-RES_, (float)(r0 + k + 1), d);
            float w0 = __expf(-GAMMA_ * t0 * t0);
            float w1 = __expf(-GAMMA_ * t1 * t1);
            a0 = fmaf(w0, wr[k * 65],       a0);
            a1 = fmaf(w1, wr[(k + 1) * 65], a1);
        }
        su[sub * 64 + c] = sp_f(a0 + a1);
        __syncthreads();

        // f2[o] = sp( sum_h Wd2[o][h] * u[h] + bd2[o] ), o = lane; Wd2T from
        // LDS (conflict-free: consecutive lanes -> consecutive banks)
        const float* uu = su + sub * 64;
        float p0 = bd2[c], p1 = 0.f;
        #pragma unroll
        for (int h = 0; h < 64; h += 2) {
            p0 = fmaf(sWd2T[h * 65 + c],       uu[h],     p0);   // uu: broadcast
            p1 = fmaf(sWd2T[(h + 1) * 65 + c], uu[h + 1], p1);
        }
        if (s < TPTS) {
            float val = sp_f(p0 + p1);
            float* T2 = ws + T2_OFF;
            T2[s * 128 + 2 * c] = val;                       // x of pair row s
            if (s > 0) T2[(s - 1) * 128 + 2 * c + 1] = val;  // y of pair row s-1
        }
    } else {
        // ---- transpose W2, W3 ----
        for (int e = tid; e < 4096; e += 256) {
            int o = e >> 6, cc = e & 63;
            ws[W2T_OFF + cc * 64 + o] = W2[e];
            ws[W3T_OFF + cc * 64 + o] = W3[e];
        }
    }
}

// ---------------------------------------------------------------------------
// main: one block per (m, j).  agg[c] = sum_i v1[m,i,c] * lerp(T, d_ij)[c]
//       table pair (f[s], f[s+1]) fetched with ONE coalesced dwordx2 load
//       then v2 = sp(agg @ W2^T + b2); out = x + v2 @ W3^T + b3
// ---------------------------------------------------------------------------
__global__ __launch_bounds__(256)
void schnet_main(const float* __restrict__ x, const float* __restrict__ dist,
                 const float* __restrict__ b2, const float* __restrict__ b3,
                 const float* __restrict__ ws, float* __restrict__ out)
{
    __shared__ float sD[64];
    __shared__ float sRed[4 * 64];
    const int m   = blockIdx.x >> 6;
    const int j   = blockIdx.x & 63;
    const int tid = threadIdx.x;
    const int c   = tid & 63;        // channel this thread owns (lane)
    const int p   = tid >> 6;        // wave = i-quarter

    if (tid < 64) sD[tid] = dist[(m * ATOM_ + tid) * ATOM_ + j];
    __syncthreads();

    const float* Tb  = ws + T2_OFF;
    const float* v1m = ws + V1_OFF + (m * 64 + p * 16) * 64;
    float acc = 0.f;
    #pragma unroll
    for (int ii = 0; ii < 16; ++ii) {
        float d  = sD[p * 16 + ii];                 // LDS broadcast
        float f  = d * INV_TSTEP;
        int   s  = min((int)f, TPTS - 2);
        float fr = f - (float)s;
        float2 t = *(const float2*)(Tb + s * 128 + 2 * c);  // coalesced 512B/wave
        float f2v = fmaf(fr, t.y - t.x, t.x);
        acc = fmaf(f2v, v1m[ii * 64 + c], acc);     // coalesced, L1/L2-hit
    }
    sRed[p * 64 + c] = acc;
    __syncthreads();
    if (tid < 64)
        sD[tid] = sRed[tid] + sRed[64 + tid] + sRed[128 + tid] + sRed[192 + tid];
    __syncthreads();

    // v2_pre = agg @ W2^T : thread (o=c, quarter=p) does 16 MACs, coalesced W2T
    {
        const float* W2t = ws + W2T_OFF;
        float s_ = 0.f;
        #pragma unroll
        for (int cc = 0; cc < 16; ++cc)
            s_ = fmaf(sD[16 * p + cc], W2t[(16 * p + cc) * 64 + c], s_);
        sRed[p * 64 + c] = s_;
    }
    __syncthreads();
    if (tid < 64)
        sD[tid] = sp_f(sRed[tid] + sRed[64 + tid] + sRed[128 + tid] + sRed[192 + tid] + b2[tid]);
    __syncthreads();
    {
        const float* W3t = ws + W3T_OFF;
        float s_ = 0.f;
        #pragma unroll
        for (int cc = 0; cc < 16; ++cc)
            s_ = fmaf(sD[16 * p + cc], W3t[(16 * p + cc) * 64 + c], s_);
        sRed[p * 64 + c] = s_;
    }
    __syncthreads();
    if (tid < 64) {
        float v_ = sRed[tid] + sRed[64 + tid] + sRed[128 + tid] + sRed[192 + tid] + b3[tid];
        out[(m * ATOM_ + j) * HID_ + tid] = v_ + x[(m * ATOM_ + j) * HID_ + tid];
    }
}

extern "C" void kernel_launch(void* const* d_in, const int* in_sizes, int n_in,
                              void* d_out, int out_size, void* d_ws, size_t ws_size,
                              hipStream_t stream) {
    const float* x   = (const float*)d_in[0];
    const float* dist= (const float*)d_in[1];
    const float* W1  = (const float*)d_in[2];
    const float* b1  = (const float*)d_in[3];
    const float* W2  = (const float*)d_in[4];
    const float* b2  = (const float*)d_in[5];
    const float* W3  = (const float*)d_in[6];
    const float* b3  = (const float*)d_in[7];
    const float* Wd1 = (const float*)d_in[8];
    const float* bd1 = (const float*)d_in[9];
    const float* Wd2 = (const float*)d_in[10];
    const float* bd2 = (const float*)d_in[11];
    float* out = (float*)d_out;
    float* ws  = (float*)d_ws;
    (void)in_sizes; (void)n_in; (void)out_size; (void)ws_size;
    // needs ~1.58 MB of d_ws (paired table + v1 + W2^T/W3^T)

    schnet_prep<<<dim3(MB_ + 501 + 1), dim3(256), 0, stream>>>(
        x, W1, b1, W2, W3, Wd1, bd1, Wd2, bd2, ws);
    schnet_main<<<dim3(MB_ * ATOM_), dim3(256), 0, stream>>>(
        x, dist, b2, b3, ws, out);
}

// Round 3
// 92.909 us; speedup vs baseline: 1.0020x; 1.0020x over previous
//
#include <hip/hip_runtime.h>
#include <math.h>

#define MB_    32
#define ATOM_  64
#define HID_   64
#define NRBF_  300
#define GAMMA_ 10.0f
#define RES_   0.1f

// filter table: f2(d) sampled at TPTS points, step TSTEP, domain [0, 10]
#define TPTS      2001
#define TSTEP     0.005f
#define INV_TSTEP 200.0f

// truncated RBF window: terms with |d - 0.1 r| > ~1.4 contribute < 5e-9
#define RWIN 28

// workspace layout (float offsets)
#define T_OFF   0
#define T_SZ    (TPTS * 64)          // 128064
#define V1_OFF  (T_OFF + T_SZ)       // 128064
#define V1_SZ   (MB_ * 64 * 64)      // 131072
#define W2T_OFF (V1_OFF + V1_SZ)     // 259136
#define W3T_OFF (W2T_OFF + 4096)     // 263232
// total 267328 floats = 1,069,312 bytes of d_ws

__device__ __forceinline__ float sp_f(float x) {
    return fmaxf(x, 0.f) + log1pf(__expf(-fabsf(x)));
}

// ---------------------------------------------------------------------------
// prep: blocks [0,32)   -> v1[m] = x[m] @ W1^T + b1   (4x4 register tile)
//       blocks [32,533) -> filter table rows, truncated-RBF, barrier-light
//       block  533      -> W2^T, W3^T for coalesced tail reads
// ---------------------------------------------------------------------------
__global__ __launch_bounds__(256)
void schnet_prep(const float* __restrict__ x,   const float* __restrict__ W1,
                 const float* __restrict__ b1,  const float* __restrict__ W2,
                 const float* __restrict__ W3,  const float* __restrict__ Wd1,
                 const float* __restrict__ bd1, const float* __restrict__ Wd2,
                 const float* __restrict__ bd2, float* __restrict__ ws)
{
    __shared__ float smem[8320];     // 33.3 KB, unioned between branches
    const int tid = threadIdx.x;
    const int b   = blockIdx.x;

    if (b < MB_) {
        // ---- v1 = x[m] @ W1^T + b1, 4x4 register tile per thread ----
        float* sx = smem;            // x[m]  [64][65] (pad -> <=2-way banks)
        float* sw = smem + 4160;     // W1    [64][65]
        const float* xm = x + b * 4096;
        for (int e = tid; e < 4096; e += 256) {
            int i = e >> 6, c = e & 63;
            sx[i * 65 + c] = xm[e];
            sw[i * 65 + c] = W1[e];
        }
        __syncthreads();
        const int tx = tid & 15;         // o-tile: o = 4*tx + bb
        const int ty = tid >> 4;         // i-tile: i = 4*ty + aa
        float acc[4][4];
        #pragma unroll
        for (int aa = 0; aa < 4; ++aa)
            #pragma unroll
            for (int bb = 0; bb < 4; ++bb)
                acc[aa][bb] = b1[4 * tx + bb];
        #pragma unroll 8
        for (int k = 0; k < 64; ++k) {
            float xa[4], wb[4];
            #pragma unroll
            for (int aa = 0; aa < 4; ++aa) xa[aa] = sx[(4 * ty + aa) * 65 + k];  // broadcast
            #pragma unroll
            for (int bb = 0; bb < 4; ++bb) wb[bb] = sw[(4 * tx + bb) * 65 + k];  // 2-way
            #pragma unroll
            for (int aa = 0; aa < 4; ++aa)
                #pragma unroll
                for (int bb = 0; bb < 4; ++bb)
                    acc[aa][bb] = fmaf(xa[aa], wb[bb], acc[aa][bb]);
        }
        #pragma unroll
        for (int aa = 0; aa < 4; ++aa) {
            float4 v = make_float4(acc[aa][0], acc[aa][1], acc[aa][2], acc[aa][3]);
            *(float4*)(ws + V1_OFF + (b * 64 + 4 * ty + aa) * 64 + 4 * tx) = v;
        }
    } else if (b < MB_ + 501) {
        // ---- table: one d-sample per wave, truncated RBF in registers ----
        float* su = smem;                // [4][64] per-wave u vectors
        const int sub = tid >> 6, c = tid & 63;
        const int s  = (b - MB_) * 4 + sub;
        const int se = min(s, TPTS - 1);         // dead waves compute, don't store
        const float d = se * TSTEP;

        int r0 = (int)ceilf((d - 1.35f) * 10.0f);
        r0 = max(r0, 0);                          // r0+RWIN-1 <= 114 < 300 always

        float a0 = bd1[c], a1 = 0.f;
        const float* wrow1 = Wd1 + c * NRBF_ + r0;
        #pragma unroll
        for (int k = 0; k < RWIN; k += 2) {
            float t0 = fmaf(-RES_, (float)(r0 + k),     d);
            float t1 = fmaf(-RES_, (float)(r0 + k + 1), d);
            float w0 = __expf(-GAMMA_ * t0 * t0);
            float w1 = __expf(-GAMMA_ * t1 * t1);
            a0 = fmaf(w0, wrow1[k],     a0);
            a1 = fmaf(w1, wrow1[k + 1], a1);
        }
        su[sub * 64 + c] = sp_f(a0 + a1);
        __syncthreads();

        // f2[o] = sp( sum_h Wd2[o][h] * u[h] + bd2[o] ), o = lane
        const float4* wrow2 = (const float4*)(Wd2 + c * 64);
        const float*  uu    = su + sub * 64;
        float s0 = bd2[c], s1 = 0.f, s2 = 0.f, s3 = 0.f;
        #pragma unroll
        for (int h4 = 0; h4 < 16; ++h4) {
            float4 wv = wrow2[h4];
            s0 = fmaf(wv.x, uu[4 * h4 + 0], s0);   // uu reads: all-lane broadcast
            s1 = fmaf(wv.y, uu[4 * h4 + 1], s1);
            s2 = fmaf(wv.z, uu[4 * h4 + 2], s2);
            s3 = fmaf(wv.w, uu[4 * h4 + 3], s3);
        }
        if (s < TPTS)
            ws[T_OFF + s * 64 + c] = sp_f((s0 + s1) + (s2 + s3));
    } else {
        // ---- transpose W2, W3 ----
        for (int e = tid; e < 4096; e += 256) {
            int o = e >> 6, c = e & 63;
            ws[W2T_OFF + c * 64 + o] = W2[e];
            ws[W3T_OFF + c * 64 + o] = W3[e];
        }
    }
}

// ---------------------------------------------------------------------------
// main: one block per (m, j).  agg[c] = sum_i v1[m,i,c] * lerp(T, d_ij)[c]
//       then v2 = sp(agg @ W2^T + b2); out = x + v2 @ W3^T + b3
// ---------------------------------------------------------------------------
__global__ __launch_bounds__(256)
void schnet_main(const float* __restrict__ x, const float* __restrict__ dist,
                 const float* __restrict__ b2, const float* __restrict__ b3,
                 const float* __restrict__ ws, float* __restrict__ out)
{
    __shared__ float sD[64];
    __shared__ float sRed[4 * 64];
    const int m   = blockIdx.x >> 6;
    const int j   = blockIdx.x & 63;
    const int tid = threadIdx.x;
    const int c   = tid & 63;        // channel this thread owns (lane)
    const int p   = tid >> 6;        // wave = i-quarter

    if (tid < 64) sD[tid] = dist[(m * ATOM_ + tid) * ATOM_ + j];
    __syncthreads();

    const float* Tb  = ws + T_OFF;
    const float* v1m = ws + V1_OFF + (m * 64 + p * 16) * 64;
    float acc = 0.f;
    #pragma unroll
    for (int ii = 0; ii < 16; ++ii) {
        float d  = sD[p * 16 + ii];                 // LDS broadcast
        float f  = d * INV_TSTEP;
        int   s  = min((int)f, TPTS - 2);
        float fr = f - (float)s;
        const float* Tr = Tb + s * 64;
        float t0 = Tr[c], t1 = Tr[64 + c];          // coalesced 256B rows
        float f2v = fmaf(fr, t1 - t0, t0);
        acc = fmaf(f2v, v1m[ii * 64 + c], acc);     // coalesced, L1/L2-hit
    }
    sRed[p * 64 + c] = acc;
    __syncthreads();
    if (tid < 64)
        sD[tid] = sRed[tid] + sRed[64 + tid] + sRed[128 + tid] + sRed[192 + tid];
    __syncthreads();

    // v2_pre = agg @ W2^T : thread (o=c, quarter=p) does 16 MACs, coalesced W2T
    {
        const float* W2t = ws + W2T_OFF;
        float s_ = 0.f;
        #pragma unroll
        for (int cc = 0; cc < 16; ++cc)
            s_ = fmaf(sD[16 * p + cc], W2t[(16 * p + cc) * 64 + c], s_);
        sRed[p * 64 + c] = s_;
    }
    __syncthreads();
    if (tid < 64)
        sD[tid] = sp_f(sRed[tid] + sRed[64 + tid] + sRed[128 + tid] + sRed[192 + tid] + b2[tid]);
    __syncthreads();
    {
        const float* W3t = ws + W3T_OFF;
        float s_ = 0.f;
        #pragma unroll
        for (int cc = 0; cc < 16; ++cc)
            s_ = fmaf(sD[16 * p + cc], W3t[(16 * p + cc) * 64 + c], s_);
        sRed[p * 64 + c] = s_;
    }
    __syncthreads();
    if (tid < 64) {
        float v_ = sRed[tid] + sRed[64 + tid] + sRed[128 + tid] + sRed[192 + tid] + b3[tid];
        out[(m * ATOM_ + j) * HID_ + tid] = v_ + x[(m * ATOM_ + j) * HID_ + tid];
    }
}

extern "C" void kernel_launch(void* const* d_in, const int* in_sizes, int n_in,
                              void* d_out, int out_size, void* d_ws, size_t ws_size,
                              hipStream_t stream) {
    const float* x   = (const float*)d_in[0];
    const float* dist= (const float*)d_in[1];
    const float* W1  = (const float*)d_in[2];
    const float* b1  = (const float*)d_in[3];
    const float* W2  = (const float*)d_in[4];
    const float* b2  = (const float*)d_in[5];
    const float* W3  = (const float*)d_in[6];
    const float* b3  = (const float*)d_in[7];
    const float* Wd1 = (const float*)d_in[8];
    const float* bd1 = (const float*)d_in[9];
    const float* Wd2 = (const float*)d_in[10];
    const float* bd2 = (const float*)d_in[11];
    float* out = (float*)d_out;
    float* ws  = (float*)d_ws;
    (void)in_sizes; (void)n_in; (void)out_size; (void)ws_size;
    // needs ~1.07 MB of d_ws (table + v1 + W2^T/W3^T)

    schnet_prep<<<dim3(MB_ + 501 + 1), dim3(256), 0, stream>>>(
        x, W1, b1, W2, W3, Wd1, bd1, Wd2, bd2, ws);
    schnet_main<<<dim3(MB_ * ATOM_), dim3(256), 0, stream>>>(
        x, dist, b2, b3, ws, out);
}